// Round 1
// baseline (511.092 us; speedup 1.0000x reference)
//
#include <hip/hip_runtime.h>

#define T_TOK 8192
#define DIM   512
#define HID   1024
#define OUTD  512
#define NE    8

typedef __attribute__((ext_vector_type(8))) short short8v;   // 8 bf16 (4 VGPRs)
typedef __attribute__((ext_vector_type(4))) float f32x4;

__device__ __forceinline__ unsigned short f2bf(float f) {
  unsigned int u = __builtin_bit_cast(unsigned int, f);
  u += 0x7fffu + ((u >> 16) & 1u);            // RNE, finite inputs
  return (unsigned short)(u >> 16);
}

__device__ __forceinline__ void gload_lds16(const void* g, void* l) {
  __builtin_amdgcn_global_load_lds(
      (__attribute__((address_space(1))) void*)g,
      (__attribute__((address_space(3))) void*)l, 16, 0, 0);
}

__device__ __forceinline__ float gelu_f(float v) {
  const float c0 = 0.7978845608028654f;       // sqrt(2/pi), jax approximate=True
  float u = c0 * (v + 0.044715f * v * v * v);
  return 0.5f * v * (1.0f + tanhf(u));
}

// ---- transpose + f32->bf16 convert: in [E][R][C] f32 -> out [E][C][R] bf16 ----
__global__ __launch_bounds__(256) void k_transpose_cvt(
    const float* __restrict__ in, unsigned short* __restrict__ outp, int R, int C) {
  __shared__ float tile[32][33];
  int e = blockIdx.z;
  const float* inE = in + (size_t)e * R * C;
  unsigned short* outE = outp + (size_t)e * R * C;
  int c0 = blockIdx.x * 32, r0 = blockIdx.y * 32;
  int x = threadIdx.x, y = threadIdx.y;
#pragma unroll
  for (int i = 0; i < 32; i += 8)
    tile[y + i][x] = inE[(size_t)(r0 + y + i) * C + (c0 + x)];
  __syncthreads();
#pragma unroll
  for (int i = 0; i < 32; i += 8)
    outE[(size_t)(c0 + y + i) * R + (r0 + x)] = f2bf(tile[x][y + i]);
}

// ---- router: one wave per token, f32 logits -> softmax -> top2 ----
__global__ __launch_bounds__(256) void k_router(
    const float* __restrict__ x, const float* __restrict__ Wg,
    int* __restrict__ top_e, float* __restrict__ top_p, int* __restrict__ counts) {
  int lane = threadIdx.x & 63;
  int t = blockIdx.x * 4 + (threadIdx.x >> 6);
  const float* xr = x + (size_t)t * DIM;
  int j0 = lane * 8;
  float4 xa = *(const float4*)(xr + j0);
  float4 xb = *(const float4*)(xr + j0 + 4);
  float xl[8] = {xa.x, xa.y, xa.z, xa.w, xb.x, xb.y, xb.z, xb.w};
  float acc[8] = {0.f,0.f,0.f,0.f,0.f,0.f,0.f,0.f};
#pragma unroll
  for (int jj = 0; jj < 8; ++jj) {
    float4 w0 = *(const float4*)(Wg + (size_t)(j0 + jj) * NE);
    float4 w1 = *(const float4*)(Wg + (size_t)(j0 + jj) * NE + 4);
    acc[0] += xl[jj] * w0.x; acc[1] += xl[jj] * w0.y;
    acc[2] += xl[jj] * w0.z; acc[3] += xl[jj] * w0.w;
    acc[4] += xl[jj] * w1.x; acc[5] += xl[jj] * w1.y;
    acc[6] += xl[jj] * w1.z; acc[7] += xl[jj] * w1.w;
  }
#pragma unroll
  for (int off = 32; off >= 1; off >>= 1) {
#pragma unroll
    for (int e2 = 0; e2 < 8; ++e2) acc[e2] += __shfl_xor(acc[e2], off, 64);
  }
  if (lane == 0) {
    float m = acc[0];
#pragma unroll
    for (int e2 = 1; e2 < 8; ++e2) m = fmaxf(m, acc[e2]);
    float p[8]; float s = 0.f;
#pragma unroll
    for (int e2 = 0; e2 < 8; ++e2) { p[e2] = expf(acc[e2] - m); s += p[e2]; }
    float inv = 1.f / s;
    int i0 = 0;
#pragma unroll
    for (int e2 = 1; e2 < 8; ++e2) if (p[e2] > p[i0]) i0 = e2;
    int i1 = (i0 == 0) ? 1 : 0;
#pragma unroll
    for (int e2 = 0; e2 < 8; ++e2) if (e2 != i0 && p[e2] > p[i1]) i1 = e2;
    top_e[t * 2] = i0;  top_e[t * 2 + 1] = i1;
    top_p[t * 2] = p[i0] * inv;  top_p[t * 2 + 1] = p[i1] * inv;
    atomicAdd(&counts[i0], 1);  atomicAdd(&counts[i1], 1);
  }
}

__global__ void k_scan(const int* __restrict__ counts, int* __restrict__ offs,
                       int* __restrict__ cursors) {
  if (threadIdx.x == 0 && blockIdx.x == 0) {
    int s = 0;
    for (int e = 0; e < NE; ++e) { offs[e] = s; cursors[e] = s; s += counts[e]; }
    offs[NE] = s;   // == 2*T_TOK always
  }
}

// ---- scatter: one wave per (token,k): claim slot, gather x row as bf16 ----
__global__ __launch_bounds__(256) void k_scatter(
    const float* __restrict__ x, const int* __restrict__ top_e,
    int* __restrict__ cursors, int* __restrict__ pos_of,
    unsigned short* __restrict__ Xp) {
  int lane = threadIdx.x & 63;
  int a = blockIdx.x * 4 + (threadIdx.x >> 6);   // 0..16383
  int t = a >> 1;
  int e = top_e[a];
  int pos = 0;
  if (lane == 0) { pos = atomicAdd(&cursors[e], 1); pos_of[a] = pos; }
  pos = __shfl(pos, 0, 64);
  const float* xr = x + (size_t)t * DIM + lane * 8;
  float4 xa = *(const float4*)xr;
  float4 xb = *(const float4*)(xr + 4);
  short8v pk;
  pk[0] = (short)f2bf(xa.x); pk[1] = (short)f2bf(xa.y);
  pk[2] = (short)f2bf(xa.z); pk[3] = (short)f2bf(xa.w);
  pk[4] = (short)f2bf(xb.x); pk[5] = (short)f2bf(xb.y);
  pk[6] = (short)f2bf(xb.z); pk[7] = (short)f2bf(xb.w);
  *(short8v*)(Xp + (size_t)pos * DIM + lane * 8) = pk;
}

// ---- NT GEMM per expert: C[M,N] = A[M,K] * Bt[N,K]^T  (m97 structure) ----
// EPI=0: +bias, gelu, store bf16 H.   EPI=1: +bias, store f32 Y.
template<int EPI>
__global__ __launch_bounds__(256, 2) void k_gemm_bt(
    const unsigned short* __restrict__ A,   // [2T][K] bf16 rows (expert-grouped)
    const unsigned short* __restrict__ Bt,  // [E][N][K] bf16
    const float* __restrict__ bias,         // [E][N]
    const int* __restrict__ offs,           // [E+1] row offsets
    unsigned short* __restrict__ Hout, float* __restrict__ Yout, int K, int N) {
  int e = blockIdx.z;
  int rowBeg = offs[e], rowEnd = offs[e + 1];
  int m0 = rowBeg + (int)blockIdx.y * 128;
  if (m0 >= rowEnd) return;
  int n0 = blockIdx.x * 128;
  const unsigned short* Be = Bt + (size_t)e * N * K;

  __shared__ __align__(16) unsigned short As[128 * 64];
  __shared__ __align__(16) unsigned short Bs[128 * 64];

  int tid = threadIdx.x, lane = tid & 63, w = tid >> 6;
  int wr = w >> 1, wc = w & 1;
  int rIn = lane >> 3;            // row within 8-row group
  int cChunk = (lane & 7) * 8;    // bf16 col offset (16B chunks)
  int fr = lane & 15, fq = lane >> 4;

  f32x4 acc[4][4];
#pragma unroll
  for (int m = 0; m < 4; ++m)
#pragma unroll
    for (int n = 0; n < 4; ++n) acc[m][n] = (f32x4){0.f, 0.f, 0.f, 0.f};

  for (int k0 = 0; k0 < K; k0 += 64) {
#pragma unroll
    for (int t4 = 0; t4 < 4; ++t4) {
      int g = w * 4 + t4;                       // 8-row group 0..15
      int ar = m0 + g * 8 + rIn;
      if (ar > rowEnd - 1) ar = rowEnd - 1;     // clamp: garbage rows never stored
      gload_lds16(A + (size_t)ar * K + k0 + cChunk, &As[g * 8 * 64]);
      int br = n0 + g * 8 + rIn;                // N is multiple of 128
      gload_lds16(Be + (size_t)br * K + k0 + cChunk, &Bs[g * 8 * 64]);
    }
    __syncthreads();
#pragma unroll
    for (int kk = 0; kk < 64; kk += 32) {
      short8v av[4], bv[4];
#pragma unroll
      for (int m = 0; m < 4; ++m)
        av[m] = *(const short8v*)&As[(wr * 64 + m * 16 + fr) * 64 + kk + fq * 8];
#pragma unroll
      for (int n = 0; n < 4; ++n)
        bv[n] = *(const short8v*)&Bs[(wc * 64 + n * 16 + fr) * 64 + kk + fq * 8];
#pragma unroll
      for (int m = 0; m < 4; ++m)
#pragma unroll
        for (int n = 0; n < 4; ++n)
          acc[m][n] = __builtin_amdgcn_mfma_f32_16x16x32_bf16(av[m], bv[n], acc[m][n], 0, 0, 0);
    }
    __syncthreads();
  }

#pragma unroll
  for (int m = 0; m < 4; ++m) {
#pragma unroll
    for (int j = 0; j < 4; ++j) {
      int row = m0 + wr * 64 + m * 16 + fq * 4 + j;
      if (row >= rowEnd) continue;
#pragma unroll
      for (int n = 0; n < 4; ++n) {
        int col = n0 + wc * 64 + n * 16 + fr;
        float v = acc[m][n][j] + bias[(size_t)e * N + col];
        if (EPI == 0) {
          Hout[(size_t)row * N + col] = f2bf(gelu_f(v));
        } else {
          Yout[(size_t)row * N + col] = v;
        }
      }
    }
  }
}

// ---- combine: out[t] = g0*Y[p0] + g1*Y[p1] (deterministic, no atomics) ----
__global__ __launch_bounds__(256) void k_combine(
    const float* __restrict__ Y, const int* __restrict__ pos_of,
    const float* __restrict__ top_p, float* __restrict__ out) {
  int lane = threadIdx.x & 63;
  int t = blockIdx.x * 4 + (threadIdx.x >> 6);
  int p0 = pos_of[t * 2], p1 = pos_of[t * 2 + 1];
  float g0 = top_p[t * 2], g1 = top_p[t * 2 + 1];
  const float4* y0 = (const float4*)(Y + (size_t)p0 * OUTD + lane * 8);
  const float4* y1 = (const float4*)(Y + (size_t)p1 * OUTD + lane * 8);
  float4* o = (float4*)(out + (size_t)t * OUTD + lane * 8);
  float4 a0 = y0[0], a1 = y0[1], c0 = y1[0], c1 = y1[1];
  float4 r0, r1;
  r0.x = g0 * a0.x + g1 * c0.x; r0.y = g0 * a0.y + g1 * c0.y;
  r0.z = g0 * a0.z + g1 * c0.z; r0.w = g0 * a0.w + g1 * c0.w;
  r1.x = g0 * a1.x + g1 * c1.x; r1.y = g0 * a1.y + g1 * c1.y;
  r1.z = g0 * a1.z + g1 * c1.z; r1.w = g0 * a1.w + g1 * c1.w;
  o[0] = r0; o[1] = r1;
}

extern "C" void kernel_launch(void* const* d_in, const int* in_sizes, int n_in,
                              void* d_out, int out_size, void* d_ws, size_t ws_size,
                              hipStream_t stream) {
  const float* x  = (const float*)d_in[0];   // [T, D]
  const float* Wg = (const float*)d_in[1];   // [D, E]
  const float* W1 = (const float*)d_in[2];   // [E, D, H]
  const float* b1 = (const float*)d_in[3];   // [E, H]
  const float* W2 = (const float*)d_in[4];   // [E, H, O]
  const float* b2 = (const float*)d_in[5];   // [E, O]
  float* out = (float*)d_out;                // [T, O]

  char* p = (char*)d_ws;
  auto take = [&](size_t bytes) { char* r = p; p += (bytes + 255) & ~(size_t)255; return r; };
  unsigned short* W1t = (unsigned short*)take((size_t)NE * DIM * HID * 2);   // [E][H][D]
  unsigned short* W2t = (unsigned short*)take((size_t)NE * HID * OUTD * 2);  // [E][O][H]
  unsigned short* Xp  = (unsigned short*)take((size_t)2 * T_TOK * DIM * 2);  // [2T][D]
  unsigned short* Hb  = (unsigned short*)take((size_t)2 * T_TOK * HID * 2);  // [2T][H]
  float*          Yb  = (float*)take((size_t)2 * T_TOK * OUTD * 4);          // [2T][O]
  int* ctrl   = (int*)take(4096);
  int* counts = ctrl; int* cursors = ctrl + 8; int* offs = ctrl + 16;
  int*   top_e  = (int*)take((size_t)2 * T_TOK * 4);
  float* top_pv = (float*)take((size_t)2 * T_TOK * 4);
  int*   pos_of = (int*)take((size_t)2 * T_TOK * 4);

  hipMemsetAsync(ctrl, 0, 64, stream);
  k_transpose_cvt<<<dim3(HID / 32, DIM / 32, NE), dim3(32, 8), 0, stream>>>(W1, W1t, DIM, HID);
  k_transpose_cvt<<<dim3(OUTD / 32, HID / 32, NE), dim3(32, 8), 0, stream>>>(W2, W2t, HID, OUTD);
  k_router<<<T_TOK / 4, 256, 0, stream>>>(x, Wg, top_e, top_pv, counts);
  k_scan<<<1, 64, 0, stream>>>(counts, offs, cursors);
  k_scatter<<<(2 * T_TOK) / 4, 256, 0, stream>>>(x, top_e, cursors, pos_of, Xp);
  k_gemm_bt<0><<<dim3(HID / 128, 64, NE), 256, 0, stream>>>(Xp, W1t, b1, offs, Hb, nullptr, DIM, HID);
  k_gemm_bt<1><<<dim3(OUTD / 128, 64, NE), 256, 0, stream>>>(Hb, W2t, b2, offs, nullptr, Yb, HID, OUTD);
  k_combine<<<T_TOK / 4, 256, 0, stream>>>(Yb, pos_of, top_pv, out);
}

// Round 2
// 154.081 us; speedup vs baseline: 3.3170x; 3.3170x over previous
//
#include <hip/hip_runtime.h>

#define T_TOK 8192
#define DIM   512
#define HID   1024
#define OUTD  512
#define NE    8

typedef __attribute__((ext_vector_type(8))) short short8v;   // 8 bf16 (4 VGPRs)
typedef __attribute__((ext_vector_type(4))) float f32x4;

__device__ __forceinline__ unsigned short f2bf(float f) {
  unsigned int u = __builtin_bit_cast(unsigned int, f);
  u += 0x7fffu + ((u >> 16) & 1u);            // RNE, finite inputs
  return (unsigned short)(u >> 16);
}

__device__ __forceinline__ void gload_lds16(const void* g, void* l) {
  __builtin_amdgcn_global_load_lds(
      (__attribute__((address_space(1))) void*)g,
      (__attribute__((address_space(3))) void*)l, 16, 0, 0);
}

__device__ __forceinline__ float gelu_f(float v) {
  const float c0 = 0.7978845608028654f;       // sqrt(2/pi), jax approximate=True
  float u = c0 * (v + 0.044715f * v * v * v);
  return 0.5f * v * (1.0f + tanhf(u));
}

// ---- transpose + f32->bf16 convert: in [E][R][C] f32 -> out [E][C][R] bf16 ----
__global__ __launch_bounds__(256) void k_transpose_cvt(
    const float* __restrict__ in, unsigned short* __restrict__ outp, int R, int C) {
  __shared__ float tile[32][33];
  int e = blockIdx.z;
  const float* inE = in + (size_t)e * R * C;
  unsigned short* outE = outp + (size_t)e * R * C;
  int c0 = blockIdx.x * 32, r0 = blockIdx.y * 32;
  int x = threadIdx.x, y = threadIdx.y;
#pragma unroll
  for (int i = 0; i < 32; i += 8)
    tile[y + i][x] = inE[(size_t)(r0 + y + i) * C + (c0 + x)];
  __syncthreads();
#pragma unroll
  for (int i = 0; i < 32; i += 8)
    outE[(size_t)(c0 + y + i) * R + (r0 + x)] = f2bf(tile[x][y + i]);
}

// ---- router: one wave per token, f32 logits -> softmax -> top2 (NO atomics) ----
__global__ __launch_bounds__(256) void k_router(
    const float* __restrict__ x, const float* __restrict__ Wg,
    int* __restrict__ top_e, float* __restrict__ top_p) {
  int lane = threadIdx.x & 63;
  int t = blockIdx.x * 4 + (threadIdx.x >> 6);
  const float* xr = x + (size_t)t * DIM;
  int j0 = lane * 8;
  float4 xa = *(const float4*)(xr + j0);
  float4 xb = *(const float4*)(xr + j0 + 4);
  float xl[8] = {xa.x, xa.y, xa.z, xa.w, xb.x, xb.y, xb.z, xb.w};
  float acc[8] = {0.f,0.f,0.f,0.f,0.f,0.f,0.f,0.f};
#pragma unroll
  for (int jj = 0; jj < 8; ++jj) {
    float4 w0 = *(const float4*)(Wg + (size_t)(j0 + jj) * NE);
    float4 w1 = *(const float4*)(Wg + (size_t)(j0 + jj) * NE + 4);
    acc[0] += xl[jj] * w0.x; acc[1] += xl[jj] * w0.y;
    acc[2] += xl[jj] * w0.z; acc[3] += xl[jj] * w0.w;
    acc[4] += xl[jj] * w1.x; acc[5] += xl[jj] * w1.y;
    acc[6] += xl[jj] * w1.z; acc[7] += xl[jj] * w1.w;
  }
#pragma unroll
  for (int off = 32; off >= 1; off >>= 1) {
#pragma unroll
    for (int e2 = 0; e2 < 8; ++e2) acc[e2] += __shfl_xor(acc[e2], off, 64);
  }
  if (lane == 0) {
    float m = acc[0];
#pragma unroll
    for (int e2 = 1; e2 < 8; ++e2) m = fmaxf(m, acc[e2]);
    float p[8]; float s = 0.f;
#pragma unroll
    for (int e2 = 0; e2 < 8; ++e2) { p[e2] = expf(acc[e2] - m); s += p[e2]; }
    float inv = 1.f / s;
    int i0 = 0;
#pragma unroll
    for (int e2 = 1; e2 < 8; ++e2) if (p[e2] > p[i0]) i0 = e2;
    int i1 = (i0 == 0) ? 1 : 0;
#pragma unroll
    for (int e2 = 0; e2 < 8; ++e2) if (e2 != i0 && p[e2] > p[i1]) i1 = e2;
    top_e[t * 2] = i0;  top_e[t * 2 + 1] = i1;
    top_p[t * 2] = p[i0] * inv;  top_p[t * 2 + 1] = p[i1] * inv;
  }
}

// ---- plan: deterministic local ranks via ballot, per-block expert counts ----
__global__ __launch_bounds__(256) void k_plan(
    const int* __restrict__ top_e, int* __restrict__ localRank,
    int* __restrict__ blockCounts) {
  __shared__ int cnt[4][NE];
  __shared__ int wbase[4][NE];
  int tid = threadIdx.x, lane = tid & 63, w = tid >> 6;
  int a = blockIdx.x * 256 + tid;
  int e = top_e[a];
  int rank = 0;
#pragma unroll
  for (int e2 = 0; e2 < NE; ++e2) {
    unsigned long long m = __ballot(e == e2);
    if (e == e2) rank = __popcll(m & ((1ULL << lane) - 1ULL));
    if (lane == 0) cnt[w][e2] = __popcll(m);
  }
  __syncthreads();
  if (tid < NE) {
    int s = 0;
#pragma unroll
    for (int w2 = 0; w2 < 4; ++w2) { wbase[w2][tid] = s; s += cnt[w2][tid]; }
    blockCounts[blockIdx.x * NE + tid] = s;
  }
  __syncthreads();
  localRank[a] = wbase[w][e] + rank;
}

// ---- scan: per-expert prefix over 64 blocks + global expert offsets ----
__global__ void k_scan2(const int* __restrict__ blockCounts, int* __restrict__ baseBlk,
                        int* __restrict__ offs, int nBlocks) {
  __shared__ int tot[NE];
  int tid = threadIdx.x;
  if (tid < NE) {
    int s = 0;
    for (int b = 0; b < nBlocks; ++b) { baseBlk[b * NE + tid] = s; s += blockCounts[b * NE + tid]; }
    tot[tid] = s;
  }
  __syncthreads();
  if (tid == 0) {
    int s = 0;
    for (int e = 0; e < NE; ++e) { offs[e] = s; s += tot[e]; }
    offs[NE] = s;   // == 2*T_TOK
  }
}

// ---- scatter: pos = offs[e] + baseBlk[b][e] + localRank (NO atomics) ----
__global__ __launch_bounds__(256) void k_scatter(
    const float* __restrict__ x, const int* __restrict__ top_e,
    const int* __restrict__ localRank, const int* __restrict__ baseBlk,
    const int* __restrict__ offs, int* __restrict__ pos_of,
    unsigned short* __restrict__ Xp) {
  int lane = threadIdx.x & 63;
  int a = blockIdx.x * 4 + (threadIdx.x >> 6);   // 0..16383
  int t = a >> 1;
  int e = top_e[a];
  int pos = offs[e] + baseBlk[(a >> 8) * NE + e] + localRank[a];
  if (lane == 0) pos_of[a] = pos;
  const float* xr = x + (size_t)t * DIM + lane * 8;
  float4 xa = *(const float4*)xr;
  float4 xb = *(const float4*)(xr + 4);
  short8v pk;
  pk[0] = (short)f2bf(xa.x); pk[1] = (short)f2bf(xa.y);
  pk[2] = (short)f2bf(xa.z); pk[3] = (short)f2bf(xa.w);
  pk[4] = (short)f2bf(xb.x); pk[5] = (short)f2bf(xb.y);
  pk[6] = (short)f2bf(xb.z); pk[7] = (short)f2bf(xb.w);
  *(short8v*)(Xp + (size_t)pos * DIM + lane * 8) = pk;
}

// ---- NT GEMM per expert: C[M,N] = A[M,K] * Bt[N,K]^T  (m97 structure) ----
// EPI=0: +bias, gelu, store bf16 H.   EPI=1: +bias, store f32 Y.
template<int EPI>
__global__ __launch_bounds__(256, 2) void k_gemm_bt(
    const unsigned short* __restrict__ A,   // [2T][K] bf16 rows (expert-grouped)
    const unsigned short* __restrict__ Bt,  // [E][N][K] bf16
    const float* __restrict__ bias,         // [E][N]
    const int* __restrict__ offs,           // [E+1] row offsets
    unsigned short* __restrict__ Hout, float* __restrict__ Yout, int K, int N) {
  int e = blockIdx.z;
  int rowBeg = offs[e], rowEnd = offs[e + 1];
  int m0 = rowBeg + (int)blockIdx.y * 128;
  if (m0 >= rowEnd) return;
  int n0 = blockIdx.x * 128;
  const unsigned short* Be = Bt + (size_t)e * N * K;

  __shared__ __align__(16) unsigned short As[128 * 64];
  __shared__ __align__(16) unsigned short Bs[128 * 64];

  int tid = threadIdx.x, lane = tid & 63, w = tid >> 6;
  int wr = w >> 1, wc = w & 1;
  int rIn = lane >> 3;            // row within 8-row group
  int cChunk = (lane & 7) * 8;    // bf16 col offset (16B chunks)
  int fr = lane & 15, fq = lane >> 4;

  f32x4 acc[4][4];
#pragma unroll
  for (int m = 0; m < 4; ++m)
#pragma unroll
    for (int n = 0; n < 4; ++n) acc[m][n] = (f32x4){0.f, 0.f, 0.f, 0.f};

  for (int k0 = 0; k0 < K; k0 += 64) {
#pragma unroll
    for (int t4 = 0; t4 < 4; ++t4) {
      int g = w * 4 + t4;                       // 8-row group 0..15
      int ar = m0 + g * 8 + rIn;
      if (ar > rowEnd - 1) ar = rowEnd - 1;     // clamp: garbage rows never stored
      gload_lds16(A + (size_t)ar * K + k0 + cChunk, &As[g * 8 * 64]);
      int br = n0 + g * 8 + rIn;                // N is multiple of 128
      gload_lds16(Be + (size_t)br * K + k0 + cChunk, &Bs[g * 8 * 64]);
    }
    __syncthreads();
#pragma unroll
    for (int kk = 0; kk < 64; kk += 32) {
      short8v av[4], bv[4];
#pragma unroll
      for (int m = 0; m < 4; ++m)
        av[m] = *(const short8v*)&As[(wr * 64 + m * 16 + fr) * 64 + kk + fq * 8];
#pragma unroll
      for (int n = 0; n < 4; ++n)
        bv[n] = *(const short8v*)&Bs[(wc * 64 + n * 16 + fr) * 64 + kk + fq * 8];
#pragma unroll
      for (int m = 0; m < 4; ++m)
#pragma unroll
        for (int n = 0; n < 4; ++n)
          acc[m][n] = __builtin_amdgcn_mfma_f32_16x16x32_bf16(av[m], bv[n], acc[m][n], 0, 0, 0);
    }
    __syncthreads();
  }

#pragma unroll
  for (int m = 0; m < 4; ++m) {
#pragma unroll
    for (int j = 0; j < 4; ++j) {
      int row = m0 + wr * 64 + m * 16 + fq * 4 + j;
      if (row >= rowEnd) continue;
#pragma unroll
      for (int n = 0; n < 4; ++n) {
        int col = n0 + wc * 64 + n * 16 + fr;
        float v = acc[m][n][j] + bias[(size_t)e * N + col];
        if (EPI == 0) {
          Hout[(size_t)row * N + col] = f2bf(gelu_f(v));
        } else {
          Yout[(size_t)row * N + col] = v;
        }
      }
    }
  }
}

// ---- combine: out[t] = g0*Y[p0] + g1*Y[p1] (deterministic, no atomics) ----
__global__ __launch_bounds__(256) void k_combine(
    const float* __restrict__ Y, const int* __restrict__ pos_of,
    const float* __restrict__ top_p, float* __restrict__ out) {
  int lane = threadIdx.x & 63;
  int t = blockIdx.x * 4 + (threadIdx.x >> 6);
  int p0 = pos_of[t * 2], p1 = pos_of[t * 2 + 1];
  float g0 = top_p[t * 2], g1 = top_p[t * 2 + 1];
  const float4* y0 = (const float4*)(Y + (size_t)p0 * OUTD + lane * 8);
  const float4* y1 = (const float4*)(Y + (size_t)p1 * OUTD + lane * 8);
  float4* o = (float4*)(out + (size_t)t * OUTD + lane * 8);
  float4 a0 = y0[0], a1 = y0[1], c0 = y1[0], c1 = y1[1];
  float4 r0, r1;
  r0.x = g0 * a0.x + g1 * c0.x; r0.y = g0 * a0.y + g1 * c0.y;
  r0.z = g0 * a0.z + g1 * c0.z; r0.w = g0 * a0.w + g1 * c0.w;
  r1.x = g0 * a1.x + g1 * c1.x; r1.y = g0 * a1.y + g1 * c1.y;
  r1.z = g0 * a1.z + g1 * c1.z; r1.w = g0 * a1.w + g1 * c1.w;
  o[0] = r0; o[1] = r1;
}

extern "C" void kernel_launch(void* const* d_in, const int* in_sizes, int n_in,
                              void* d_out, int out_size, void* d_ws, size_t ws_size,
                              hipStream_t stream) {
  const float* x  = (const float*)d_in[0];   // [T, D]
  const float* Wg = (const float*)d_in[1];   // [D, E]
  const float* W1 = (const float*)d_in[2];   // [E, D, H]
  const float* b1 = (const float*)d_in[3];   // [E, H]
  const float* W2 = (const float*)d_in[4];   // [E, H, O]
  const float* b2 = (const float*)d_in[5];   // [E, O]
  float* out = (float*)d_out;                // [T, O]

  char* p = (char*)d_ws;
  auto take = [&](size_t bytes) { char* r = p; p += (bytes + 255) & ~(size_t)255; return r; };
  unsigned short* W1t = (unsigned short*)take((size_t)NE * DIM * HID * 2);   // [E][H][D]
  unsigned short* W2t = (unsigned short*)take((size_t)NE * HID * OUTD * 2);  // [E][O][H]
  unsigned short* Xp  = (unsigned short*)take((size_t)2 * T_TOK * DIM * 2);  // [2T][D]
  unsigned short* Hb  = (unsigned short*)take((size_t)2 * T_TOK * HID * 2);  // [2T][H]
  float*          Yb  = (float*)take((size_t)2 * T_TOK * OUTD * 4);          // [2T][O]
  int* offs = (int*)take(4096);
  int*   top_e  = (int*)take((size_t)2 * T_TOK * 4);
  float* top_pv = (float*)take((size_t)2 * T_TOK * 4);
  int*   pos_of = (int*)take((size_t)2 * T_TOK * 4);
  int* localRank   = (int*)take((size_t)2 * T_TOK * 4);
  int* blockCounts = (int*)take((size_t)64 * NE * 4);
  int* baseBlk     = (int*)take((size_t)64 * NE * 4);

  const int PLAN_BLOCKS = (2 * T_TOK) / 256;   // 64

  k_transpose_cvt<<<dim3(HID / 32, DIM / 32, NE), dim3(32, 8), 0, stream>>>(W1, W1t, DIM, HID);
  k_transpose_cvt<<<dim3(OUTD / 32, HID / 32, NE), dim3(32, 8), 0, stream>>>(W2, W2t, HID, OUTD);
  k_router<<<T_TOK / 4, 256, 0, stream>>>(x, Wg, top_e, top_pv);
  k_plan<<<PLAN_BLOCKS, 256, 0, stream>>>(top_e, localRank, blockCounts);
  k_scan2<<<1, 64, 0, stream>>>(blockCounts, baseBlk, offs, PLAN_BLOCKS);
  k_scatter<<<(2 * T_TOK) / 4, 256, 0, stream>>>(x, top_e, localRank, baseBlk, offs, pos_of, Xp);
  k_gemm_bt<0><<<dim3(HID / 128, 64, NE), 256, 0, stream>>>(Xp, W1t, b1, offs, Hb, nullptr, DIM, HID);
  k_gemm_bt<1><<<dim3(OUTD / 128, 64, NE), 256, 0, stream>>>(Hb, W2t, b2, offs, nullptr, Yb, HID, OUTD);
  k_combine<<<T_TOK / 4, 256, 0, stream>>>(Yb, pos_of, top_pv, out);
}